// Round 1
// 467.429 us; speedup vs baseline: 1.0643x; 1.0643x over previous
//
#include <hip/hip_runtime.h>

#define D 1024
#define TPB 256           // 4 waves per block
#define NBLOCKS 2048      // 256 CU x 8 blocks/CU resident -> persistent grid-stride

// Trivially-copyable 16B vector so __builtin_nontemporal_load works (HIP's float4
// is a non-trivial class; clang's builtin needs a plain vector type).
typedef float f4 __attribute__((ext_vector_type(4)));

__global__ __launch_bounds__(TPB, 4) void CosineSimilarity_76785425318088_kernel(
    const float* __restrict__ premise,
    const float* __restrict__ hypothesis,
    float* __restrict__ out,
    int n_rows) {
    const int wave = threadIdx.x >> 6;     // wave = 64 lanes on CDNA
    const int lane = threadIdx.x & 63;
    const int waves_per_block = TPB >> 6;
    const int nwaves = gridDim.x * waves_per_block;   // total waves in grid
    int row = blockIdx.x * waves_per_block + wave;
    if (row >= n_rows) return;

    const f4* __restrict__ pbase = reinterpret_cast<const f4*>(premise);
    const f4* __restrict__ hbase = reinterpret_cast<const f4*>(hypothesis);
    const int QF = D / 4;   // 256 float4 per row; 64 lanes -> 4 chunks of 64

    // ---- prologue: load row 0 of this wave's stride set ----
    f4 pa0, pa1, pa2, pa3, pb0, pb1, pb2, pb3;
    {
        const f4* pr = pbase + (size_t)row * QF + lane;
        const f4* hr = hbase + (size_t)row * QF + lane;
        pa0 = __builtin_nontemporal_load(pr);
        pb0 = __builtin_nontemporal_load(hr);
        pa1 = __builtin_nontemporal_load(pr + 64);
        pb1 = __builtin_nontemporal_load(hr + 64);
        pa2 = __builtin_nontemporal_load(pr + 128);
        pb2 = __builtin_nontemporal_load(hr + 128);
        pa3 = __builtin_nontemporal_load(pr + 192);
        pb3 = __builtin_nontemporal_load(hr + 192);
    }

    for (;;) {
        const int nrow = row + nwaves;            // wave-uniform -> no divergence
        const bool have_next = (nrow < n_rows);

        // ---- issue next row's 16 loads BEFORE touching current row's data ----
        // Keeps ~16 KB/wave in flight; reduce/sqrt tail hides under HBM latency.
        f4 na0, na1, na2, na3, nb0, nb1, nb2, nb3;
        if (have_next) {
            const f4* pr = pbase + (size_t)nrow * QF + lane;
            const f4* hr = hbase + (size_t)nrow * QF + lane;
            na0 = __builtin_nontemporal_load(pr);
            nb0 = __builtin_nontemporal_load(hr);
            na1 = __builtin_nontemporal_load(pr + 64);
            nb1 = __builtin_nontemporal_load(hr + 64);
            na2 = __builtin_nontemporal_load(pr + 128);
            nb2 = __builtin_nontemporal_load(hr + 128);
            na3 = __builtin_nontemporal_load(pr + 192);
            nb3 = __builtin_nontemporal_load(hr + 192);
        }

        // ---- compute current row ----
        float dot = 0.f, pp = 0.f, hh = 0.f;
#define ACC(A, B)                                                                  \
        dot = fmaf(A.x, B.x, dot); pp = fmaf(A.x, A.x, pp); hh = fmaf(B.x, B.x, hh); \
        dot = fmaf(A.y, B.y, dot); pp = fmaf(A.y, A.y, pp); hh = fmaf(B.y, B.y, hh); \
        dot = fmaf(A.z, B.z, dot); pp = fmaf(A.z, A.z, pp); hh = fmaf(B.z, B.z, hh); \
        dot = fmaf(A.w, B.w, dot); pp = fmaf(A.w, A.w, pp); hh = fmaf(B.w, B.w, hh);
        ACC(pa0, pb0) ACC(pa1, pb1) ACC(pa2, pb2) ACC(pa3, pb3)
#undef ACC

        // Wave-64 reduction (3 independent chains interleave on the DS pipe).
#pragma unroll
        for (int off = 32; off > 0; off >>= 1) {
            dot += __shfl_down(dot, off, 64);
            pp  += __shfl_down(pp,  off, 64);
            hh  += __shfl_down(hh,  off, 64);
        }

        if (lane == 0) {
            const float eps = 1e-12f;
            float denom = fmaxf(sqrtf(pp), eps) * fmaxf(sqrtf(hh), eps);
            out[row] = dot / denom;
        }

        if (!have_next) break;
        row = nrow;
        pa0 = na0; pa1 = na1; pa2 = na2; pa3 = na3;   // register rename, no copy cost
        pb0 = nb0; pb1 = nb1; pb2 = nb2; pb3 = nb3;
    }
}

extern "C" void kernel_launch(void* const* d_in, const int* in_sizes, int n_in,
                              void* d_out, int out_size, void* d_ws, size_t ws_size,
                              hipStream_t stream) {
    const float* premise    = (const float*)d_in[0];
    const float* hypothesis = (const float*)d_in[1];
    float* out = (float*)d_out;
    const int n_rows = out_size;  // 65536

    const int waves_per_block = TPB >> 6;
    int blocks = NBLOCKS;
    int max_useful = (n_rows + waves_per_block - 1) / waves_per_block;
    if (blocks > max_useful) blocks = max_useful;

    CosineSimilarity_76785425318088_kernel<<<blocks, TPB, 0, stream>>>(
        premise, hypothesis, out, n_rows);
}